// Round 6
// baseline (485.388 us; speedup 1.0000x reference)
//
#include <hip/hip_runtime.h>

#define NN 50000
#define EE 800000
#define NEG 0.2f
#define CAP 128   // per-wave LDS edge stash (deg ~Poisson(16), max ~45; fallback kept)
#define NB 782    // ceil(NN/64) buckets for CSR build
#define BSH 6     // bucket = dst >> 6

typedef long long i64;
typedef unsigned int u32;
typedef unsigned short u16;

static __device__ __forceinline__ float wave_max64(float v) {
#pragma unroll
  for (int m = 32; m >= 1; m >>= 1) v = fmaxf(v, __shfl_xor(v, m, 64));
  return v;
}
static __device__ __forceinline__ float wave_sum64(float v) {
#pragma unroll
  for (int m = 32; m >= 1; m >>= 1) v += __shfl_xor(v, m, 64);
  return v;
}

// bf16 helpers
static __device__ __forceinline__ u16 f2bf(float f) {
  u32 u = __float_as_uint(f);
  u += 0x7FFFu + ((u >> 16) & 1u);
  return (u16)(u >> 16);
}
// dword holding two bf16: lo = feature 2k, hi = feature 2k+1
static __device__ __forceinline__ float bflo(u32 v) { return __uint_as_float(v << 16); }
static __device__ __forceinline__ float bfhi(u32 v) { return __uint_as_float(v & 0xffff0000u); }

// ---- dtype probe: int64 vs int32 -----------------------------------------
__global__ void k_probe(const void* ei, int* flag) {
  __shared__ int sbad[4];
  int t = threadIdx.x;
  const i64* p = (const i64*)ei;
  i64 v = p[t];
  int bad = (v < 0 || v >= NN) ? 1 : 0;
  unsigned long long b = __ballot(bad);
  if ((t & 63) == 0) sbad[t >> 6] = (b != 0ULL);
  __syncthreads();
  if (t == 0) *flag = !(sbad[0] | sbad[1] | sbad[2] | sbad[3]);
}

static __device__ __forceinline__ int edge_at(const void* ei, int is64, int idx) {
  return is64 ? (int)((const i64*)ei)[idx] : ((const int*)ei)[idx];
}

// ---- CSR build: bucketed counting sort -----------------------------------
// pass 1: per-block LDS histogram of buckets -> bhist[block][NB]
__global__ void k_bcount(const void* ei, const int* flag, int* bhist) {
  __shared__ int h[NB];
  int blk = blockIdx.x;  // 0..255
  for (int i = threadIdx.x; i < NB; i += 256) h[i] = 0;
  __syncthreads();
  int is64 = *flag;
  const int chunk = (EE + 255) / 256;
  int lo = blk * chunk, hi = min(lo + chunk, EE);
  for (int e = lo + threadIdx.x; e < hi; e += 256) {
    int d = edge_at(ei, is64, EE + e);
    atomicAdd(&h[d >> BSH], 1);
  }
  __syncthreads();
  for (int i = threadIdx.x; i < NB; i += 256) bhist[blk * NB + i] = h[i];
}

// pass 2: column-sum over 256 blocks + exclusive prefix over NB buckets
__global__ void k_bscan(const int* bhist, int* bstart, int* bcur, int* rowp) {
  __shared__ int tot[NB];
  __shared__ int sc[1024];
  int t = threadIdx.x;  // 0..1023
  for (int i = t; i < NB; i += 1024) {
    int s = 0;
    for (int k = 0; k < 256; ++k) s += bhist[k * NB + i];
    tot[i] = s;
  }
  __syncthreads();
  sc[t] = (t < NB) ? tot[t] : 0;
  __syncthreads();
  for (int off = 1; off < 1024; off <<= 1) {
    int v = (t >= off) ? sc[t - off] : 0;
    __syncthreads();
    sc[t] += v;
    __syncthreads();
  }
  if (t < NB) {
    int excl = sc[t] - tot[t];
    bstart[t] = excl;
    bcur[t] = excl;
  }
  if (t == NB - 1) { bstart[NB] = sc[t]; rowp[NN] = sc[t]; }
}

// pass 3: scatter packed (dlocal<<20 | src) into bucket regions
__global__ void k_bfill(const void* ei, const int* flag, int* bcur, u32* buf) {
  int e = blockIdx.x * blockDim.x + threadIdx.x;
  if (e >= EE) return;
  int is64 = *flag;
  int s = edge_at(ei, is64, e);
  int d = edge_at(ei, is64, EE + e);
  int pos = atomicAdd(&bcur[d >> BSH], 1);
  buf[pos] = (u32)s | ((u32)(d & 63) << 20);
}

// pass 4: per-bucket local sort -> rowp, dinv, csr (contiguous ~4KB writes)
__global__ void k_csr(const u32* __restrict__ buf, const int* __restrict__ bstart,
                      int* __restrict__ rowp, float* __restrict__ dinv,
                      int* __restrict__ csr) {
  __shared__ int degl[64], offl[64], curl[64];
  int b = blockIdx.x;
  int base = b << BSH;
  int nn = min(64, NN - base);
  int lo = bstart[b], hi = bstart[b + 1];
  int t = threadIdx.x;
  if (t < 64) { degl[t] = 0; curl[t] = 0; }
  __syncthreads();
  for (int i = lo + t; i < hi; i += 256) {
    atomicAdd(&degl[buf[i] >> 20], 1);
  }
  __syncthreads();
  if (t < 64) {
    int x = degl[t];
    int incl = x;
#pragma unroll
    for (int off = 1; off < 64; off <<= 1) {
      int y = __shfl_up(incl, off, 64);
      if (t >= off) incl += y;
    }
    offl[t] = incl - x;
    if (t < nn) {
      rowp[base + t] = lo + incl - x;
      dinv[base + t] = rsqrtf((float)(x + 1));
    }
  }
  __syncthreads();
  for (int i = lo + t; i < hi; i += 256) {
    u32 v = buf[i];
    int dl = v >> 20;
    int pos = atomicAdd(&curl[dl], 1);
    csr[lo + offl[dl] + pos] = v & 0xFFFFF;
  }
}

// ---- dense GEMM: Y(bf16)[n][OC] = X(f32)[n][K] @ W[K][OC] ----------------
template <int K, int OC, int ROWS>
__global__ void k_gemm(const float* __restrict__ X, const float* __restrict__ W,
                       u16* __restrict__ Y, int n) {
  __shared__ __align__(16) float Wl[K * OC];
  int t = threadIdx.x;
  for (int i = t; i < K * OC / 4; i += 256)
    ((float4*)Wl)[i] = ((const float4*)W)[i];
  __syncthreads();

  const int CP = OC / 2;
  const int RP = 256 / CP;
  int tx = t % CP, ty = t / CP;
  int blockRow = blockIdx.x * ROWS;
  const float2* Wl2 = (const float2*)Wl;

  for (int rp = 0; rp < ROWS; rp += RP * 2) {
    int r0 = blockRow + rp + ty * 2;
    if (r0 >= n) break;
    int r1 = r0 + 1;
    bool has1 = (r1 < n);
    const float4* x0q = (const float4*)(X + (size_t)r0 * K);
    const float4* x1q = (const float4*)(X + (size_t)(has1 ? r1 : r0) * K);
    float a00 = 0.f, a01 = 0.f, a10 = 0.f, a11 = 0.f;
#pragma unroll 4
    for (int k4 = 0; k4 < K / 4; ++k4) {
      float4 xa = x0q[k4];
      float4 xb = x1q[k4];
      const float* pa = &xa.x;
      const float* pb = &xb.x;
#pragma unroll
      for (int j = 0; j < 4; ++j) {
        float2 w2 = Wl2[(k4 * 4 + j) * CP + tx];
        a00 += pa[j] * w2.x; a01 += pa[j] * w2.y;
        a10 += pb[j] * w2.x; a11 += pb[j] * w2.y;
      }
    }
    ((ushort2*)(Y + (size_t)r0 * OC))[tx] = make_ushort2(f2bf(a00), f2bf(a01));
    if (has1) ((ushort2*)(Y + (size_t)r1 * OC))[tx] = make_ushort2(f2bf(a10), f2bf(a11));
  }
}

// ---- GEMM + fused attention-coefficient epilogue -------------------------
template <int K, int OC, int ROWS, int G>
__global__ void k_gemm_att(const float* __restrict__ X, const float* __restrict__ W,
                           const float* __restrict__ aw_s, const float* __restrict__ aw_d,
                           u16* __restrict__ Y, float* __restrict__ a_sv,
                           float* __restrict__ a_dv, int n) {
  __shared__ __align__(16) float Wl[K * OC];
  int t = threadIdx.x;
  for (int i = t; i < K * OC / 4; i += 256)
    ((float4*)Wl)[i] = ((const float4*)W)[i];
  __syncthreads();

  const int CP = OC / 2;
  const int RP = 256 / CP;
  int tx = t % CP, ty = t / CP;
  int blockRow = blockIdx.x * ROWS;
  const float2* Wl2 = (const float2*)Wl;
  float2 aws2 = ((const float2*)aw_s)[tx];
  float2 awd2 = ((const float2*)aw_d)[tx];
  int hh = (tx / G) & 1;

  for (int rp = 0; rp < ROWS; rp += RP * 2) {
    int r0 = blockRow + rp + ty * 2;
    if (r0 >= n) break;
    int r1 = r0 + 1;
    bool has1 = (r1 < n);
    const float4* x0q = (const float4*)(X + (size_t)r0 * K);
    const float4* x1q = (const float4*)(X + (size_t)(has1 ? r1 : r0) * K);
    float a00 = 0.f, a01 = 0.f, a10 = 0.f, a11 = 0.f;
#pragma unroll 4
    for (int k4 = 0; k4 < K / 4; ++k4) {
      float4 xa = x0q[k4];
      float4 xb = x1q[k4];
      const float* pa = &xa.x;
      const float* pb = &xb.x;
#pragma unroll
      for (int j = 0; j < 4; ++j) {
        float2 w2 = Wl2[(k4 * 4 + j) * CP + tx];
        a00 += pa[j] * w2.x; a01 += pa[j] * w2.y;
        a10 += pb[j] * w2.x; a11 += pb[j] * w2.y;
      }
    }
    ((ushort2*)(Y + (size_t)r0 * OC))[tx] = make_ushort2(f2bf(a00), f2bf(a01));
    if (has1) ((ushort2*)(Y + (size_t)r1 * OC))[tx] = make_ushort2(f2bf(a10), f2bf(a11));

    float sp0 = a00 * aws2.x + a01 * aws2.y;
    float dp0 = a00 * awd2.x + a01 * awd2.y;
    float sp1 = a10 * aws2.x + a11 * aws2.y;
    float dp1 = a10 * awd2.x + a11 * awd2.y;
#pragma unroll
    for (int mm = G / 2; mm >= 1; mm >>= 1) {
      sp0 += __shfl_xor(sp0, mm, 64); dp0 += __shfl_xor(dp0, mm, 64);
      sp1 += __shfl_xor(sp1, mm, 64); dp1 += __shfl_xor(dp1, mm, 64);
    }
    if ((tx & (G - 1)) == 0) {
      a_sv[r0 * 2 + hh] = sp0; a_dv[r0 * 2 + hh] = dp0;
      if (has1) { a_sv[r1 * 2 + hh] = sp1; a_dv[r1 * 2 + hh] = dp1; }
    }
  }
}

// ---- GCN aggregation: wave/node; halves alternate edges; unroll 4 --------
__global__ void k_gcn(const u16* __restrict__ g, const float* __restrict__ dinv,
                      const int* __restrict__ rowp, const int* __restrict__ csr,
                      const float* __restrict__ bias, float* __restrict__ out) {
  __shared__ int   s_src[4][CAP];
  __shared__ float s_wt[4][CAP];
  int wid = (blockIdx.x * blockDim.x + threadIdx.x) >> 6;
  int w = (threadIdx.x >> 6) & 3;
  int lane = threadIdx.x & 63;
  if (wid >= NN) return;
  float di = dinv[wid];
  int beg = rowp[wid], cnt = rowp[wid + 1] - beg;
  int c1 = min(cnt, CAP);

  for (int idx = lane; idx < c1; idx += 64) {
    int s = csr[beg + idx];
    s_src[w][idx] = s; s_wt[w][idx] = dinv[s];
  }

  int half = lane >> 5, fp = lane & 31;
  const u32* g2 = (const u32*)g;   // 32 dwords per node row
  float acc0 = 0.f, acc1 = 0.f;
  int idx = half;
  for (; idx + 6 < c1; idx += 8) {
    int sA = s_src[w][idx],     sB = s_src[w][idx + 2];
    int sC = s_src[w][idx + 4], sD = s_src[w][idx + 6];
    float wA = s_wt[w][idx],     wB = s_wt[w][idx + 2];
    float wC = s_wt[w][idx + 4], wD = s_wt[w][idx + 6];
    u32 vA = g2[(size_t)sA * 32 + fp], vB = g2[(size_t)sB * 32 + fp];
    u32 vC = g2[(size_t)sC * 32 + fp], vD = g2[(size_t)sD * 32 + fp];
    acc0 += bflo(vA) * wA + bflo(vB) * wB + bflo(vC) * wC + bflo(vD) * wD;
    acc1 += bfhi(vA) * wA + bfhi(vB) * wB + bfhi(vC) * wC + bfhi(vD) * wD;
  }
  for (; idx < c1; idx += 2) {
    int s = s_src[w][idx]; float ws = s_wt[w][idx];
    u32 v = g2[(size_t)s * 32 + fp];
    acc0 += bflo(v) * ws; acc1 += bfhi(v) * ws;
  }
  for (idx = CAP + half; idx < cnt; idx += 2) {  // essentially never
    int s = csr[beg + idx];
    float ws = dinv[s];
    u32 v = g2[(size_t)s * 32 + fp];
    acc0 += bflo(v) * ws; acc1 += bfhi(v) * ws;
  }
  if (half == 0) {  // self loop
    u32 v = g2[(size_t)wid * 32 + fp];
    acc0 += bflo(v) * di; acc1 += bfhi(v) * di;
  }
  acc0 += __shfl_xor(acc0, 32, 64);
  acc1 += __shfl_xor(acc1, 32, 64);
  if (half == 0) {
    float v0 = fmaxf(acc0 * di + bias[2 * fp], 0.f);
    float v1 = fmaxf(acc1 * di + bias[2 * fp + 1], 0.f);
    ((float2*)(out + (size_t)wid * 64))[fp] = make_float2(v0, v1);
  }
}

// ---- GAT layer 1: wave per node, both heads; lane = dword 0..63 ----------
__global__ void k_gat1(const u16* __restrict__ hg, const float* __restrict__ a_s,
                       const float* __restrict__ a_d, const int* __restrict__ rowp,
                       const int* __restrict__ csr, const float* __restrict__ bias,
                       float* __restrict__ out) {
  __shared__ int   s_src[4][CAP];
  __shared__ float s_x0[4][CAP];
  __shared__ float s_x1[4][CAP];
  int wid = (blockIdx.x * blockDim.x + threadIdx.x) >> 6;
  int w = (threadIdx.x >> 6) & 3;
  int lane = threadIdx.x & 63;
  if (wid >= NN) return;
  int beg = rowp[wid], cnt = rowp[wid + 1] - beg;
  int tot = cnt + 1;
  int c1 = min(tot, CAP);
  float ad0 = a_d[wid * 2], ad1 = a_d[wid * 2 + 1];
  float m0, m1, inv0, inv1;

  if (tot <= 64) {  // fast path
    bool act = lane < tot;
    int s = (lane < cnt) ? csr[beg + lane] : wid;
    float e0 = -1e30f, e1 = -1e30f;
    if (act) {
      float2 av = ((const float2*)a_s)[s];
      e0 = av.x + ad0; e0 = e0 > 0.f ? e0 : NEG * e0;
      e1 = av.y + ad1; e1 = e1 > 0.f ? e1 : NEG * e1;
    }
    m0 = wave_max64(e0); m1 = wave_max64(e1);
    float x0 = act ? __expf(e0 - m0) : 0.f;
    float x1 = act ? __expf(e1 - m1) : 0.f;
    inv0 = 1.f / wave_sum64(x0); inv1 = 1.f / wave_sum64(x1);
    if (act) { s_src[w][lane] = s; s_x0[w][lane] = x0; s_x1[w][lane] = x1; }
  } else {  // generic fallback
    float mm0 = -1e30f, mm1 = -1e30f;
    for (int idx = lane; idx < tot; idx += 64) {
      int s = (idx < cnt) ? csr[beg + idx] : wid;
      float2 av = ((const float2*)a_s)[s];
      float e0 = av.x + ad0; e0 = e0 > 0.f ? e0 : NEG * e0;
      float e1 = av.y + ad1; e1 = e1 > 0.f ? e1 : NEG * e1;
      if (idx < CAP) { s_src[w][idx] = s; s_x0[w][idx] = e0; s_x1[w][idx] = e1; }
      mm0 = fmaxf(mm0, e0); mm1 = fmaxf(mm1, e1);
    }
    m0 = wave_max64(mm0); m1 = wave_max64(mm1);
    float ss0 = 0.f, ss1 = 0.f;
    for (int idx = lane; idx < c1; idx += 64) {
      float x0 = __expf(s_x0[w][idx] - m0), x1 = __expf(s_x1[w][idx] - m1);
      s_x0[w][idx] = x0; s_x1[w][idx] = x1;
      ss0 += x0; ss1 += x1;
    }
    for (int idx = CAP + lane; idx < tot; idx += 64) {
      int s = (idx < cnt) ? csr[beg + idx] : wid;
      float2 av = ((const float2*)a_s)[s];
      float e0 = av.x + ad0; e0 = e0 > 0.f ? e0 : NEG * e0;
      float e1 = av.y + ad1; e1 = e1 > 0.f ? e1 : NEG * e1;
      ss0 += __expf(e0 - m0); ss1 += __expf(e1 - m1);
    }
    inv0 = 1.f / wave_sum64(ss0); inv1 = 1.f / wave_sum64(ss1);
  }

  bool hi = (lane >= 32);
  float invh = hi ? inv1 : inv0, mh = hi ? m1 : m0, adh = hi ? ad1 : ad0;
  const u32* hg2 = (const u32*)hg;  // 64 dwords per node row
  float acc0 = 0.f, acc1 = 0.f;
  int idx = 0;
  for (; idx + 3 < c1; idx += 4) {
    int sA = s_src[w][idx],     sB = s_src[w][idx + 1];
    int sC = s_src[w][idx + 2], sD = s_src[w][idx + 3];
    float aA = hi ? s_x1[w][idx]     : s_x0[w][idx];
    float aB = hi ? s_x1[w][idx + 1] : s_x0[w][idx + 1];
    float aC = hi ? s_x1[w][idx + 2] : s_x0[w][idx + 2];
    float aD = hi ? s_x1[w][idx + 3] : s_x0[w][idx + 3];
    u32 vA = hg2[(size_t)sA * 64 + lane], vB = hg2[(size_t)sB * 64 + lane];
    u32 vC = hg2[(size_t)sC * 64 + lane], vD = hg2[(size_t)sD * 64 + lane];
    acc0 += bflo(vA) * aA + bflo(vB) * aB + bflo(vC) * aC + bflo(vD) * aD;
    acc1 += bfhi(vA) * aA + bfhi(vB) * aB + bfhi(vC) * aC + bfhi(vD) * aD;
  }
  for (; idx < c1; ++idx) {
    int s = s_src[w][idx];
    float a = hi ? s_x1[w][idx] : s_x0[w][idx];
    u32 v = hg2[(size_t)s * 64 + lane];
    acc0 += bflo(v) * a; acc1 += bfhi(v) * a;
  }
  for (; idx < tot; ++idx) {  // beyond CAP
    int s = (idx < cnt) ? csr[beg + idx] : wid;
    float e = (hi ? a_s[s * 2 + 1] : a_s[s * 2]) + adh;
    e = e > 0.f ? e : NEG * e;
    float a = __expf(e - mh);
    u32 v = hg2[(size_t)s * 64 + lane];
    acc0 += bflo(v) * a; acc1 += bfhi(v) * a;
  }
  float v0 = fmaxf(acc0 * invh + bias[2 * lane], 0.f);
  float v1 = fmaxf(acc1 * invh + bias[2 * lane + 1], 0.f);
  ((float2*)(out + (size_t)wid * 128))[lane] = make_float2(v0, v1);
}

// ---- GAT layer 2 (H=2,C=32, head-mean) + log_softmax ---------------------
__global__ void k_gat2(const u16* __restrict__ hg, const float* __restrict__ a_s,
                       const float* __restrict__ a_d, const int* __restrict__ rowp,
                       const int* __restrict__ csr, const float* __restrict__ bias,
                       float* __restrict__ out) {
  __shared__ int   s_src[4][CAP];
  __shared__ float s_x0[4][CAP];
  __shared__ float s_x1[4][CAP];
  int wid = (blockIdx.x * blockDim.x + threadIdx.x) >> 6;
  int w = (threadIdx.x >> 6) & 3;
  int lane = threadIdx.x & 63;
  if (wid >= NN) return;
  int beg = rowp[wid], cnt = rowp[wid + 1] - beg;
  int tot = cnt + 1;
  int c1 = min(tot, CAP);
  float ad0 = a_d[wid * 2], ad1 = a_d[wid * 2 + 1];
  float m0, m1, inv0, inv1;

  if (tot <= 64) {
    bool act = lane < tot;
    int s = (lane < cnt) ? csr[beg + lane] : wid;
    float e0 = -1e30f, e1 = -1e30f;
    if (act) {
      float2 av = ((const float2*)a_s)[s];
      e0 = av.x + ad0; e0 = e0 > 0.f ? e0 : NEG * e0;
      e1 = av.y + ad1; e1 = e1 > 0.f ? e1 : NEG * e1;
    }
    m0 = wave_max64(e0); m1 = wave_max64(e1);
    float x0 = act ? __expf(e0 - m0) : 0.f;
    float x1 = act ? __expf(e1 - m1) : 0.f;
    inv0 = 1.f / wave_sum64(x0); inv1 = 1.f / wave_sum64(x1);
    if (act) { s_src[w][lane] = s; s_x0[w][lane] = x0; s_x1[w][lane] = x1; }
  } else {
    float mm0 = -1e30f, mm1 = -1e30f;
    for (int idx = lane; idx < tot; idx += 64) {
      int s = (idx < cnt) ? csr[beg + idx] : wid;
      float2 av = ((const float2*)a_s)[s];
      float e0 = av.x + ad0; e0 = e0 > 0.f ? e0 : NEG * e0;
      float e1 = av.y + ad1; e1 = e1 > 0.f ? e1 : NEG * e1;
      if (idx < CAP) { s_src[w][idx] = s; s_x0[w][idx] = e0; s_x1[w][idx] = e1; }
      mm0 = fmaxf(mm0, e0); mm1 = fmaxf(mm1, e1);
    }
    m0 = wave_max64(mm0); m1 = wave_max64(mm1);
    float ss0 = 0.f, ss1 = 0.f;
    for (int idx = lane; idx < c1; idx += 64) {
      float x0 = __expf(s_x0[w][idx] - m0), x1 = __expf(s_x1[w][idx] - m1);
      s_x0[w][idx] = x0; s_x1[w][idx] = x1;
      ss0 += x0; ss1 += x1;
    }
    for (int idx = CAP + lane; idx < tot; idx += 64) {
      int s = (idx < cnt) ? csr[beg + idx] : wid;
      float2 av = ((const float2*)a_s)[s];
      float e0 = av.x + ad0; e0 = e0 > 0.f ? e0 : NEG * e0;
      float e1 = av.y + ad1; e1 = e1 > 0.f ? e1 : NEG * e1;
      ss0 += __expf(e0 - m0); ss1 += __expf(e1 - m1);
    }
    inv0 = 1.f / wave_sum64(ss0); inv1 = 1.f / wave_sum64(ss1);
  }

  int half = lane >> 5, fp = lane & 31;
  int hh2 = fp >> 4;
  float invh = hh2 ? inv1 : inv0;
  float mh = hh2 ? m1 : m0;
  float adh = hh2 ? ad1 : ad0;

  const u32* hg2 = (const u32*)hg;  // 32 dwords per node row
  float acc0 = 0.f, acc1 = 0.f;
  int idx = half;
  for (; idx + 6 < c1; idx += 8) {
    int sA = s_src[w][idx],     sB = s_src[w][idx + 2];
    int sC = s_src[w][idx + 4], sD = s_src[w][idx + 6];
    float aA = hh2 ? s_x1[w][idx]     : s_x0[w][idx];
    float aB = hh2 ? s_x1[w][idx + 2] : s_x0[w][idx + 2];
    float aC = hh2 ? s_x1[w][idx + 4] : s_x0[w][idx + 4];
    float aD = hh2 ? s_x1[w][idx + 6] : s_x0[w][idx + 6];
    u32 vA = hg2[(size_t)sA * 32 + fp], vB = hg2[(size_t)sB * 32 + fp];
    u32 vC = hg2[(size_t)sC * 32 + fp], vD = hg2[(size_t)sD * 32 + fp];
    acc0 += bflo(vA) * aA + bflo(vB) * aB + bflo(vC) * aC + bflo(vD) * aD;
    acc1 += bfhi(vA) * aA + bfhi(vB) * aB + bfhi(vC) * aC + bfhi(vD) * aD;
  }
  for (; idx < c1; idx += 2) {
    int s = s_src[w][idx];
    float a = hh2 ? s_x1[w][idx] : s_x0[w][idx];
    u32 v = hg2[(size_t)s * 32 + fp];
    acc0 += bflo(v) * a; acc1 += bfhi(v) * a;
  }
  for (idx = CAP + half; idx < tot; idx += 2) {
    int s = (idx < cnt) ? csr[beg + idx] : wid;
    float e = a_s[s * 2 + hh2] + adh;
    e = e > 0.f ? e : NEG * e;
    float a = __expf(e - mh);
    u32 v = hg2[(size_t)s * 32 + fp];
    acc0 += bflo(v) * a; acc1 += bfhi(v) * a;
  }
  acc0 += __shfl_xor(acc0, 32, 64);
  acc1 += __shfl_xor(acc1, 32, 64);

  float v0 = acc0 * invh, v1 = acc1 * invh;
  v0 = 0.5f * (v0 + __shfl_xor(v0, 16, 64));   // head mean
  v1 = 0.5f * (v1 + __shfl_xor(v1, 16, 64));
  int c0 = 2 * (fp & 15);
  v0 += bias[c0]; v1 += bias[c0 + 1];
  float mx = fmaxf(v0, v1);
#pragma unroll
  for (int m = 8; m >= 1; m >>= 1) mx = fmaxf(mx, __shfl_xor(mx, m, 64));
  float se = __expf(v0 - mx) + __expf(v1 - mx);
#pragma unroll
  for (int m = 8; m >= 1; m >>= 1) se += __shfl_xor(se, m, 64);
  float lse = mx + __logf(se);
  if (lane < 16) ((float2*)(out + (size_t)wid * 32))[fp] = make_float2(v0 - lse, v1 - lse);
}

// --------------------------------------------------------------------------
extern "C" void kernel_launch(void* const* d_in, const int* in_sizes, int n_in,
                              void* d_out, int out_size, void* d_ws, size_t ws_size,
                              hipStream_t stream) {
  (void)in_sizes; (void)n_in; (void)out_size; (void)ws_size;
  const float* x   = (const float*)d_in[0];
  const void*  ei  = d_in[1];
  const float* W1  = (const float*)d_in[2];
  const float* b1  = (const float*)d_in[3];
  const float* W2  = (const float*)d_in[4];
  const float* b2  = (const float*)d_in[5];
  const float* Wg1 = (const float*)d_in[6];
  const float* as1 = (const float*)d_in[7];
  const float* ad1 = (const float*)d_in[8];
  const float* bg1 = (const float*)d_in[9];
  const float* Wg2 = (const float*)d_in[10];
  const float* as2 = (const float*)d_in[11];
  const float* ad2 = (const float*)d_in[12];
  const float* bg2 = (const float*)d_in[13];
  float* out = (float*)d_out;

  char* w = (char*)d_ws;
  auto alloc = [&](size_t bytes) { char* p = w; w += (bytes + 255) & ~(size_t)255; return p; };
  u16* Hb     = (u16*)alloc((size_t)NN * 128 * 2);
  float* Hf   = (float*)alloc((size_t)NN * 128 * 4);
  float* dinv = (float*)alloc((size_t)NN * 4);
  float* asb  = (float*)alloc((size_t)NN * 2 * 4);
  float* adb  = (float*)alloc((size_t)NN * 2 * 4);
  int* rowp   = (int*)alloc((size_t)(NN + 1) * 4);
  int* csr    = (int*)alloc((size_t)EE * 4);
  u32* buf    = (u32*)alloc((size_t)EE * 4);
  int* bhist  = (int*)alloc((size_t)256 * NB * 4);
  int* bstart = (int*)alloc((size_t)(NB + 1) * 4);
  int* bcur   = (int*)alloc((size_t)NB * 4);
  int* flag   = (int*)alloc(16);

  const int TB = 256;
  int gE = (EE + TB - 1) / TB;
  int gW = (NN + 3) / 4;          // wave per node
  int gG = (NN + 63) / 64;        // gemm blocks

  // CSR build (bucketed counting sort)
  k_probe<<<1, 256, 0, stream>>>(ei, flag);
  k_bcount<<<256, 256, 0, stream>>>(ei, flag, bhist);
  k_bscan<<<1, 1024, 0, stream>>>(bhist, bstart, bcur, rowp);
  k_bfill<<<gE, TB, 0, stream>>>(ei, flag, bcur, buf);
  k_csr<<<NB, 256, 0, stream>>>(buf, bstart, rowp, dinv, csr);

  // GCN 1
  k_gemm<128, 64, 64><<<gG, TB, 0, stream>>>(x, W1, Hb, NN);
  k_gcn<<<gW, TB, 0, stream>>>(Hb, dinv, rowp, csr, b1, Hf);
  // GCN 2
  k_gemm<64, 64, 64><<<gG, TB, 0, stream>>>(Hf, W2, Hb, NN);
  k_gcn<<<gW, TB, 0, stream>>>(Hb, dinv, rowp, csr, b2, Hf);
  // GAT 1 (concat, relu): gemm + fused att coefficients
  k_gemm_att<64, 128, 64, 32><<<gG, TB, 0, stream>>>(Hf, Wg1, as1, ad1, Hb, asb, adb, NN);
  k_gat1<<<gW, TB, 0, stream>>>(Hb, asb, adb, rowp, csr, bg1, Hf);
  // GAT 2 (head mean) + log_softmax
  k_gemm_att<128, 64, 64, 16><<<gG, TB, 0, stream>>>(Hf, Wg2, as2, ad2, Hb, asb, adb, NN);
  k_gat2<<<gW, TB, 0, stream>>>(Hb, asb, adb, rowp, csr, bg2, out);
}

// Round 7
// 306.069 us; speedup vs baseline: 1.5859x; 1.5859x over previous
//
#include <hip/hip_runtime.h>

#define NN 50000
#define EE 800000
#define NEG 0.2f
#define CAP 128    // per-wave LDS edge stash (deg ~Poisson(16), max ~45; fallback kept)
#define NBC 98     // coarse buckets of 512 nodes for CSR build
#define BSH2 9
#define CAPB 16384 // buf capacity per bucket (mean 8163, std ~90 -> 91 sigma margin)
#define PCH 3125   // edges per k_part block (256 * 3125 == EE exactly)

typedef long long i64;
typedef unsigned int u32;
typedef unsigned short u16;

static __device__ __forceinline__ float wave_max64(float v) {
#pragma unroll
  for (int m = 32; m >= 1; m >>= 1) v = fmaxf(v, __shfl_xor(v, m, 64));
  return v;
}
static __device__ __forceinline__ float wave_sum64(float v) {
#pragma unroll
  for (int m = 32; m >= 1; m >>= 1) v += __shfl_xor(v, m, 64);
  return v;
}

// bf16 helpers
static __device__ __forceinline__ u16 f2bf(float f) {
  u32 u = __float_as_uint(f);
  u += 0x7FFFu + ((u >> 16) & 1u);
  return (u16)(u >> 16);
}
static __device__ __forceinline__ float bflo(u32 v) { return __uint_as_float(v << 16); }
static __device__ __forceinline__ float bfhi(u32 v) { return __uint_as_float(v & 0xffff0000u); }

// ---- dtype probe + zero bucket counters ----------------------------------
__global__ void k_probe(const void* ei, int* flag, int* gcnt) {
  __shared__ int sbad[4];
  int t = threadIdx.x;
  if (t < NBC) gcnt[t] = 0;
  const i64* p = (const i64*)ei;
  i64 v = p[t];
  int bad = (v < 0 || v >= NN) ? 1 : 0;
  unsigned long long b = __ballot(bad);
  if ((t & 63) == 0) sbad[t >> 6] = (b != 0ULL);
  __syncthreads();
  if (t == 0) *flag = !(sbad[0] | sbad[1] | sbad[2] | sbad[3]);
}

static __device__ __forceinline__ int edge_at(const void* ei, int is64, int idx) {
  return is64 ? (int)((const i64*)ei)[idx] : ((const int*)ei)[idx];
}

// ---- pass 1: per-block LDS counting sort into 98 coarse buckets ----------
// packed u32: src (16b) | dlocal (9b) << 16 | bucket (7b) << 25
__global__ void k_part(const void* ei, const int* flag, int* gcnt, u32* buf) {
  __shared__ u32 lbuf[PCH];
  __shared__ int hist[128], offb[128], curb[128], gbase[128], sc[128];
  int t = threadIdx.x;
  int is64 = *flag;
  if (t < 128) { hist[t] = 0; curb[t] = 0; }
  __syncthreads();
  int lo = blockIdx.x * PCH;

  // A: histogram of dst buckets
  for (int e = lo + t; e < lo + PCH; e += 256)
    atomicAdd(&hist[edge_at(ei, is64, EE + e) >> BSH2], 1);
  __syncthreads();

  // scan 128
  if (t < 128) sc[t] = hist[t];
  __syncthreads();
  for (int o = 1; o < 128; o <<= 1) {
    int v = (t >= o && t < 128) ? sc[t - o] : 0;
    __syncthreads();
    if (t < 128) sc[t] += v;
    __syncthreads();
  }
  if (t < 128) offb[t] = sc[t] - hist[t];
  __syncthreads();

  // B: place packed edges into LDS-sorted buffer
  for (int e = lo + t; e < lo + PCH; e += 256) {
    int s = edge_at(ei, is64, e);
    int d = edge_at(ei, is64, EE + e);
    int b = d >> BSH2;
    u32 v = (u32)s | ((u32)(d & 511) << 16) | ((u32)b << 25);
    int p = atomicAdd(&curb[b], 1);
    lbuf[offb[b] + p] = v;
  }
  __syncthreads();

  // reserve global runs: ONE atomic per (block,bucket)
  if (t < 128) {
    int c = hist[t];
    gbase[t] = c ? atomicAdd(&gcnt[t], c) : 0;
  }
  __syncthreads();

  // flush contiguous runs
  for (int i = t; i < PCH; i += 256) {
    u32 v = lbuf[i];
    int b = v >> 25;
    int pos = gbase[b] + (i - offb[b]);
    if (pos < CAPB) buf[(size_t)b * CAPB + pos] = v;
  }
}

// ---- pass 2: exclusive scan of bucket counts -> csr bases ----------------
__global__ void k_scanb(const int* gcnt, int* csrbase, int* rowp) {
  __shared__ int sc[128];
  int t = threadIdx.x;  // 128 threads
  int c = (t < NBC) ? min(gcnt[t], CAPB) : 0;
  sc[t] = c;
  __syncthreads();
  for (int o = 1; o < 128; o <<= 1) {
    int v = (t >= o) ? sc[t - o] : 0;
    __syncthreads();
    sc[t] += v;
    __syncthreads();
  }
  if (t < NBC) csrbase[t] = sc[t] - c;
  if (t == 127) rowp[NN] = sc[127];
}

// ---- pass 3: per-bucket local sort -> rowp, dinv, csr --------------------
__global__ void k_csr2(const u32* __restrict__ buf, const int* __restrict__ gcnt,
                       const int* __restrict__ csrbase, int* __restrict__ rowp,
                       float* __restrict__ dinv, int* __restrict__ csr) {
  __shared__ int hist[512], offs[512], cur[512], sc[256];
  int b = blockIdx.x;
  int t = threadIdx.x;  // 256 threads
  int cnt = min(gcnt[b], CAPB);
  const u32* mb = buf + (size_t)b * CAPB;
  int cbase = csrbase[b];
  int nbase = b << BSH2;
  int nn = min(512, NN - nbase);
  hist[t] = 0; hist[t + 256] = 0; cur[t] = 0; cur[t + 256] = 0;
  __syncthreads();
  for (int i = t; i < cnt; i += 256) atomicAdd(&hist[(mb[i] >> 16) & 511], 1);
  __syncthreads();
  int a0 = hist[2 * t], a1 = hist[2 * t + 1];
  sc[t] = a0 + a1;
  __syncthreads();
  for (int o = 1; o < 256; o <<= 1) {
    int v = (t >= o) ? sc[t - o] : 0;
    __syncthreads();
    sc[t] += v;
    __syncthreads();
  }
  int excl = sc[t] - (a0 + a1);
  offs[2 * t] = excl; offs[2 * t + 1] = excl + a0;
  __syncthreads();
  for (int i = t; i < nn; i += 256) {
    rowp[nbase + i] = cbase + offs[i];
    dinv[nbase + i] = rsqrtf((float)(hist[i] + 1));
  }
  for (int i = t; i < cnt; i += 256) {
    u32 v = mb[i];
    int dl = (v >> 16) & 511;
    int p = atomicAdd(&cur[dl], 1);
    csr[cbase + offs[dl] + p] = (int)(v & 0xFFFF);
  }
}

// ---- dense GEMM: Y(bf16)[n][OC] = X(f32)[n][K] @ W[K][OC] ----------------
template <int K, int OC, int ROWS>
__global__ void k_gemm(const float* __restrict__ X, const float* __restrict__ W,
                       u16* __restrict__ Y, int n) {
  __shared__ __align__(16) float Wl[K * OC];
  int t = threadIdx.x;
  for (int i = t; i < K * OC / 4; i += 256)
    ((float4*)Wl)[i] = ((const float4*)W)[i];
  __syncthreads();

  const int CP = OC / 2;
  const int RP = 256 / CP;
  int tx = t % CP, ty = t / CP;
  int blockRow = blockIdx.x * ROWS;
  const float2* Wl2 = (const float2*)Wl;

  for (int rp = 0; rp < ROWS; rp += RP * 2) {
    int r0 = blockRow + rp + ty * 2;
    if (r0 >= n) break;
    int r1 = r0 + 1;
    bool has1 = (r1 < n);
    const float4* x0q = (const float4*)(X + (size_t)r0 * K);
    const float4* x1q = (const float4*)(X + (size_t)(has1 ? r1 : r0) * K);
    float a00 = 0.f, a01 = 0.f, a10 = 0.f, a11 = 0.f;
#pragma unroll 4
    for (int k4 = 0; k4 < K / 4; ++k4) {
      float4 xa = x0q[k4];
      float4 xb = x1q[k4];
      const float* pa = &xa.x;
      const float* pb = &xb.x;
#pragma unroll
      for (int j = 0; j < 4; ++j) {
        float2 w2 = Wl2[(k4 * 4 + j) * CP + tx];
        a00 += pa[j] * w2.x; a01 += pa[j] * w2.y;
        a10 += pb[j] * w2.x; a11 += pb[j] * w2.y;
      }
    }
    ((ushort2*)(Y + (size_t)r0 * OC))[tx] = make_ushort2(f2bf(a00), f2bf(a01));
    if (has1) ((ushort2*)(Y + (size_t)r1 * OC))[tx] = make_ushort2(f2bf(a10), f2bf(a11));
  }
}

// ---- GEMM + fused attention-coefficient epilogue -------------------------
template <int K, int OC, int ROWS, int G>
__global__ void k_gemm_att(const float* __restrict__ X, const float* __restrict__ W,
                           const float* __restrict__ aw_s, const float* __restrict__ aw_d,
                           u16* __restrict__ Y, float* __restrict__ a_sv,
                           float* __restrict__ a_dv, int n) {
  __shared__ __align__(16) float Wl[K * OC];
  int t = threadIdx.x;
  for (int i = t; i < K * OC / 4; i += 256)
    ((float4*)Wl)[i] = ((const float4*)W)[i];
  __syncthreads();

  const int CP = OC / 2;
  const int RP = 256 / CP;
  int tx = t % CP, ty = t / CP;
  int blockRow = blockIdx.x * ROWS;
  const float2* Wl2 = (const float2*)Wl;
  float2 aws2 = ((const float2*)aw_s)[tx];
  float2 awd2 = ((const float2*)aw_d)[tx];
  int hh = (tx / G) & 1;

  for (int rp = 0; rp < ROWS; rp += RP * 2) {
    int r0 = blockRow + rp + ty * 2;
    if (r0 >= n) break;
    int r1 = r0 + 1;
    bool has1 = (r1 < n);
    const float4* x0q = (const float4*)(X + (size_t)r0 * K);
    const float4* x1q = (const float4*)(X + (size_t)(has1 ? r1 : r0) * K);
    float a00 = 0.f, a01 = 0.f, a10 = 0.f, a11 = 0.f;
#pragma unroll 4
    for (int k4 = 0; k4 < K / 4; ++k4) {
      float4 xa = x0q[k4];
      float4 xb = x1q[k4];
      const float* pa = &xa.x;
      const float* pb = &xb.x;
#pragma unroll
      for (int j = 0; j < 4; ++j) {
        float2 w2 = Wl2[(k4 * 4 + j) * CP + tx];
        a00 += pa[j] * w2.x; a01 += pa[j] * w2.y;
        a10 += pb[j] * w2.x; a11 += pb[j] * w2.y;
      }
    }
    ((ushort2*)(Y + (size_t)r0 * OC))[tx] = make_ushort2(f2bf(a00), f2bf(a01));
    if (has1) ((ushort2*)(Y + (size_t)r1 * OC))[tx] = make_ushort2(f2bf(a10), f2bf(a11));

    float sp0 = a00 * aws2.x + a01 * aws2.y;
    float dp0 = a00 * awd2.x + a01 * awd2.y;
    float sp1 = a10 * aws2.x + a11 * aws2.y;
    float dp1 = a10 * awd2.x + a11 * awd2.y;
#pragma unroll
    for (int mm = G / 2; mm >= 1; mm >>= 1) {
      sp0 += __shfl_xor(sp0, mm, 64); dp0 += __shfl_xor(dp0, mm, 64);
      sp1 += __shfl_xor(sp1, mm, 64); dp1 += __shfl_xor(dp1, mm, 64);
    }
    if ((tx & (G - 1)) == 0) {
      a_sv[r0 * 2 + hh] = sp0; a_dv[r0 * 2 + hh] = dp0;
      if (has1) { a_sv[r1 * 2 + hh] = sp1; a_dv[r1 * 2 + hh] = dp1; }
    }
  }
}

// ---- GCN aggregation: wave/node; halves alternate edges; unroll 4 --------
__global__ void k_gcn(const u16* __restrict__ g, const float* __restrict__ dinv,
                      const int* __restrict__ rowp, const int* __restrict__ csr,
                      const float* __restrict__ bias, float* __restrict__ out) {
  __shared__ int   s_src[4][CAP];
  __shared__ float s_wt[4][CAP];
  int wid = (blockIdx.x * blockDim.x + threadIdx.x) >> 6;
  int w = (threadIdx.x >> 6) & 3;
  int lane = threadIdx.x & 63;
  if (wid >= NN) return;
  float di = dinv[wid];
  int beg = rowp[wid], cnt = rowp[wid + 1] - beg;
  int c1 = min(cnt, CAP);

  for (int idx = lane; idx < c1; idx += 64) {
    int s = csr[beg + idx];
    s_src[w][idx] = s; s_wt[w][idx] = dinv[s];
  }

  int half = lane >> 5, fp = lane & 31;
  const u32* g2 = (const u32*)g;   // 32 dwords per node row
  float acc0 = 0.f, acc1 = 0.f;
  int idx = half;
  for (; idx + 6 < c1; idx += 8) {
    int sA = s_src[w][idx],     sB = s_src[w][idx + 2];
    int sC = s_src[w][idx + 4], sD = s_src[w][idx + 6];
    float wA = s_wt[w][idx],     wB = s_wt[w][idx + 2];
    float wC = s_wt[w][idx + 4], wD = s_wt[w][idx + 6];
    u32 vA = g2[(size_t)sA * 32 + fp], vB = g2[(size_t)sB * 32 + fp];
    u32 vC = g2[(size_t)sC * 32 + fp], vD = g2[(size_t)sD * 32 + fp];
    acc0 += bflo(vA) * wA + bflo(vB) * wB + bflo(vC) * wC + bflo(vD) * wD;
    acc1 += bfhi(vA) * wA + bfhi(vB) * wB + bfhi(vC) * wC + bfhi(vD) * wD;
  }
  for (; idx < c1; idx += 2) {
    int s = s_src[w][idx]; float ws = s_wt[w][idx];
    u32 v = g2[(size_t)s * 32 + fp];
    acc0 += bflo(v) * ws; acc1 += bfhi(v) * ws;
  }
  for (idx = CAP + half; idx < cnt; idx += 2) {  // essentially never
    int s = csr[beg + idx];
    float ws = dinv[s];
    u32 v = g2[(size_t)s * 32 + fp];
    acc0 += bflo(v) * ws; acc1 += bfhi(v) * ws;
  }
  if (half == 0) {  // self loop
    u32 v = g2[(size_t)wid * 32 + fp];
    acc0 += bflo(v) * di; acc1 += bfhi(v) * di;
  }
  acc0 += __shfl_xor(acc0, 32, 64);
  acc1 += __shfl_xor(acc1, 32, 64);
  if (half == 0) {
    float v0 = fmaxf(acc0 * di + bias[2 * fp], 0.f);
    float v1 = fmaxf(acc1 * di + bias[2 * fp + 1], 0.f);
    ((float2*)(out + (size_t)wid * 64))[fp] = make_float2(v0, v1);
  }
}

// ---- GAT layer 1: wave per node, both heads; lane = dword 0..63 ----------
__global__ void k_gat1(const u16* __restrict__ hg, const float* __restrict__ a_s,
                       const float* __restrict__ a_d, const int* __restrict__ rowp,
                       const int* __restrict__ csr, const float* __restrict__ bias,
                       float* __restrict__ out) {
  __shared__ int   s_src[4][CAP];
  __shared__ float s_x0[4][CAP];
  __shared__ float s_x1[4][CAP];
  int wid = (blockIdx.x * blockDim.x + threadIdx.x) >> 6;
  int w = (threadIdx.x >> 6) & 3;
  int lane = threadIdx.x & 63;
  if (wid >= NN) return;
  int beg = rowp[wid], cnt = rowp[wid + 1] - beg;
  int tot = cnt + 1;
  int c1 = min(tot, CAP);
  float ad0 = a_d[wid * 2], ad1 = a_d[wid * 2 + 1];
  float m0, m1, inv0, inv1;

  if (tot <= 64) {  // fast path
    bool act = lane < tot;
    int s = (lane < cnt) ? csr[beg + lane] : wid;
    float e0 = -1e30f, e1 = -1e30f;
    if (act) {
      float2 av = ((const float2*)a_s)[s];
      e0 = av.x + ad0; e0 = e0 > 0.f ? e0 : NEG * e0;
      e1 = av.y + ad1; e1 = e1 > 0.f ? e1 : NEG * e1;
    }
    m0 = wave_max64(e0); m1 = wave_max64(e1);
    float x0 = act ? __expf(e0 - m0) : 0.f;
    float x1 = act ? __expf(e1 - m1) : 0.f;
    inv0 = 1.f / wave_sum64(x0); inv1 = 1.f / wave_sum64(x1);
    if (act) { s_src[w][lane] = s; s_x0[w][lane] = x0; s_x1[w][lane] = x1; }
  } else {  // generic fallback
    float mm0 = -1e30f, mm1 = -1e30f;
    for (int idx = lane; idx < tot; idx += 64) {
      int s = (idx < cnt) ? csr[beg + idx] : wid;
      float2 av = ((const float2*)a_s)[s];
      float e0 = av.x + ad0; e0 = e0 > 0.f ? e0 : NEG * e0;
      float e1 = av.y + ad1; e1 = e1 > 0.f ? e1 : NEG * e1;
      if (idx < CAP) { s_src[w][idx] = s; s_x0[w][idx] = e0; s_x1[w][idx] = e1; }
      mm0 = fmaxf(mm0, e0); mm1 = fmaxf(mm1, e1);
    }
    m0 = wave_max64(mm0); m1 = wave_max64(mm1);
    float ss0 = 0.f, ss1 = 0.f;
    for (int idx = lane; idx < c1; idx += 64) {
      float x0 = __expf(s_x0[w][idx] - m0), x1 = __expf(s_x1[w][idx] - m1);
      s_x0[w][idx] = x0; s_x1[w][idx] = x1;
      ss0 += x0; ss1 += x1;
    }
    for (int idx = CAP + lane; idx < tot; idx += 64) {
      int s = (idx < cnt) ? csr[beg + idx] : wid;
      float2 av = ((const float2*)a_s)[s];
      float e0 = av.x + ad0; e0 = e0 > 0.f ? e0 : NEG * e0;
      float e1 = av.y + ad1; e1 = e1 > 0.f ? e1 : NEG * e1;
      ss0 += __expf(e0 - m0); ss1 += __expf(e1 - m1);
    }
    inv0 = 1.f / wave_sum64(ss0); inv1 = 1.f / wave_sum64(ss1);
  }

  bool hi = (lane >= 32);
  float invh = hi ? inv1 : inv0, mh = hi ? m1 : m0, adh = hi ? ad1 : ad0;
  const u32* hg2 = (const u32*)hg;  // 64 dwords per node row
  float acc0 = 0.f, acc1 = 0.f;
  int idx = 0;
  for (; idx + 3 < c1; idx += 4) {
    int sA = s_src[w][idx],     sB = s_src[w][idx + 1];
    int sC = s_src[w][idx + 2], sD = s_src[w][idx + 3];
    float aA = hi ? s_x1[w][idx]     : s_x0[w][idx];
    float aB = hi ? s_x1[w][idx + 1] : s_x0[w][idx + 1];
    float aC = hi ? s_x1[w][idx + 2] : s_x0[w][idx + 2];
    float aD = hi ? s_x1[w][idx + 3] : s_x0[w][idx + 3];
    u32 vA = hg2[(size_t)sA * 64 + lane], vB = hg2[(size_t)sB * 64 + lane];
    u32 vC = hg2[(size_t)sC * 64 + lane], vD = hg2[(size_t)sD * 64 + lane];
    acc0 += bflo(vA) * aA + bflo(vB) * aB + bflo(vC) * aC + bflo(vD) * aD;
    acc1 += bfhi(vA) * aA + bfhi(vB) * aB + bfhi(vC) * aC + bfhi(vD) * aD;
  }
  for (; idx < c1; ++idx) {
    int s = s_src[w][idx];
    float a = hi ? s_x1[w][idx] : s_x0[w][idx];
    u32 v = hg2[(size_t)s * 64 + lane];
    acc0 += bflo(v) * a; acc1 += bfhi(v) * a;
  }
  for (; idx < tot; ++idx) {  // beyond CAP
    int s = (idx < cnt) ? csr[beg + idx] : wid;
    float e = (hi ? a_s[s * 2 + 1] : a_s[s * 2]) + adh;
    e = e > 0.f ? e : NEG * e;
    float a = __expf(e - mh);
    u32 v = hg2[(size_t)s * 64 + lane];
    acc0 += bflo(v) * a; acc1 += bfhi(v) * a;
  }
  float v0 = fmaxf(acc0 * invh + bias[2 * lane], 0.f);
  float v1 = fmaxf(acc1 * invh + bias[2 * lane + 1], 0.f);
  ((float2*)(out + (size_t)wid * 128))[lane] = make_float2(v0, v1);
}

// ---- GAT layer 2 (H=2,C=32, head-mean) + log_softmax ---------------------
__global__ void k_gat2(const u16* __restrict__ hg, const float* __restrict__ a_s,
                       const float* __restrict__ a_d, const int* __restrict__ rowp,
                       const int* __restrict__ csr, const float* __restrict__ bias,
                       float* __restrict__ out) {
  __shared__ int   s_src[4][CAP];
  __shared__ float s_x0[4][CAP];
  __shared__ float s_x1[4][CAP];
  int wid = (blockIdx.x * blockDim.x + threadIdx.x) >> 6;
  int w = (threadIdx.x >> 6) & 3;
  int lane = threadIdx.x & 63;
  if (wid >= NN) return;
  int beg = rowp[wid], cnt = rowp[wid + 1] - beg;
  int tot = cnt + 1;
  int c1 = min(tot, CAP);
  float ad0 = a_d[wid * 2], ad1 = a_d[wid * 2 + 1];
  float m0, m1, inv0, inv1;

  if (tot <= 64) {
    bool act = lane < tot;
    int s = (lane < cnt) ? csr[beg + lane] : wid;
    float e0 = -1e30f, e1 = -1e30f;
    if (act) {
      float2 av = ((const float2*)a_s)[s];
      e0 = av.x + ad0; e0 = e0 > 0.f ? e0 : NEG * e0;
      e1 = av.y + ad1; e1 = e1 > 0.f ? e1 : NEG * e1;
    }
    m0 = wave_max64(e0); m1 = wave_max64(e1);
    float x0 = act ? __expf(e0 - m0) : 0.f;
    float x1 = act ? __expf(e1 - m1) : 0.f;
    inv0 = 1.f / wave_sum64(x0); inv1 = 1.f / wave_sum64(x1);
    if (act) { s_src[w][lane] = s; s_x0[w][lane] = x0; s_x1[w][lane] = x1; }
  } else {
    float mm0 = -1e30f, mm1 = -1e30f;
    for (int idx = lane; idx < tot; idx += 64) {
      int s = (idx < cnt) ? csr[beg + idx] : wid;
      float2 av = ((const float2*)a_s)[s];
      float e0 = av.x + ad0; e0 = e0 > 0.f ? e0 : NEG * e0;
      float e1 = av.y + ad1; e1 = e1 > 0.f ? e1 : NEG * e1;
      if (idx < CAP) { s_src[w][idx] = s; s_x0[w][idx] = e0; s_x1[w][idx] = e1; }
      mm0 = fmaxf(mm0, e0); mm1 = fmaxf(mm1, e1);
    }
    m0 = wave_max64(mm0); m1 = wave_max64(mm1);
    float ss0 = 0.f, ss1 = 0.f;
    for (int idx = lane; idx < c1; idx += 64) {
      float x0 = __expf(s_x0[w][idx] - m0), x1 = __expf(s_x1[w][idx] - m1);
      s_x0[w][idx] = x0; s_x1[w][idx] = x1;
      ss0 += x0; ss1 += x1;
    }
    for (int idx = CAP + lane; idx < tot; idx += 64) {
      int s = (idx < cnt) ? csr[beg + idx] : wid;
      float2 av = ((const float2*)a_s)[s];
      float e0 = av.x + ad0; e0 = e0 > 0.f ? e0 : NEG * e0;
      float e1 = av.y + ad1; e1 = e1 > 0.f ? e1 : NEG * e1;
      ss0 += __expf(e0 - m0); ss1 += __expf(e1 - m1);
    }
    inv0 = 1.f / wave_sum64(ss0); inv1 = 1.f / wave_sum64(ss1);
  }

  int half = lane >> 5, fp = lane & 31;
  int hh2 = fp >> 4;
  float invh = hh2 ? inv1 : inv0;
  float mh = hh2 ? m1 : m0;
  float adh = hh2 ? ad1 : ad0;

  const u32* hg2 = (const u32*)hg;  // 32 dwords per node row
  float acc0 = 0.f, acc1 = 0.f;
  int idx = half;
  for (; idx + 6 < c1; idx += 8) {
    int sA = s_src[w][idx],     sB = s_src[w][idx + 2];
    int sC = s_src[w][idx + 4], sD = s_src[w][idx + 6];
    float aA = hh2 ? s_x1[w][idx]     : s_x0[w][idx];
    float aB = hh2 ? s_x1[w][idx + 2] : s_x0[w][idx + 2];
    float aC = hh2 ? s_x1[w][idx + 4] : s_x0[w][idx + 4];
    float aD = hh2 ? s_x1[w][idx + 6] : s_x0[w][idx + 6];
    u32 vA = hg2[(size_t)sA * 32 + fp], vB = hg2[(size_t)sB * 32 + fp];
    u32 vC = hg2[(size_t)sC * 32 + fp], vD = hg2[(size_t)sD * 32 + fp];
    acc0 += bflo(vA) * aA + bflo(vB) * aB + bflo(vC) * aC + bflo(vD) * aD;
    acc1 += bfhi(vA) * aA + bfhi(vB) * aB + bfhi(vC) * aC + bfhi(vD) * aD;
  }
  for (; idx < c1; idx += 2) {
    int s = s_src[w][idx];
    float a = hh2 ? s_x1[w][idx] : s_x0[w][idx];
    u32 v = hg2[(size_t)s * 32 + fp];
    acc0 += bflo(v) * a; acc1 += bfhi(v) * a;
  }
  for (idx = CAP + half; idx < tot; idx += 2) {
    int s = (idx < cnt) ? csr[beg + idx] : wid;
    float e = a_s[s * 2 + hh2] + adh;
    e = e > 0.f ? e : NEG * e;
    float a = __expf(e - mh);
    u32 v = hg2[(size_t)s * 32 + fp];
    acc0 += bflo(v) * a; acc1 += bfhi(v) * a;
  }
  acc0 += __shfl_xor(acc0, 32, 64);
  acc1 += __shfl_xor(acc1, 32, 64);

  float v0 = acc0 * invh, v1 = acc1 * invh;
  v0 = 0.5f * (v0 + __shfl_xor(v0, 16, 64));   // head mean
  v1 = 0.5f * (v1 + __shfl_xor(v1, 16, 64));
  int c0 = 2 * (fp & 15);
  v0 += bias[c0]; v1 += bias[c0 + 1];
  float mx = fmaxf(v0, v1);
#pragma unroll
  for (int m = 8; m >= 1; m >>= 1) mx = fmaxf(mx, __shfl_xor(mx, m, 64));
  float se = __expf(v0 - mx) + __expf(v1 - mx);
#pragma unroll
  for (int m = 8; m >= 1; m >>= 1) se += __shfl_xor(se, m, 64);
  float lse = mx + __logf(se);
  if (lane < 16) ((float2*)(out + (size_t)wid * 32))[fp] = make_float2(v0 - lse, v1 - lse);
}

// --------------------------------------------------------------------------
extern "C" void kernel_launch(void* const* d_in, const int* in_sizes, int n_in,
                              void* d_out, int out_size, void* d_ws, size_t ws_size,
                              hipStream_t stream) {
  (void)in_sizes; (void)n_in; (void)out_size; (void)ws_size;
  const float* x   = (const float*)d_in[0];
  const void*  ei  = d_in[1];
  const float* W1  = (const float*)d_in[2];
  const float* b1  = (const float*)d_in[3];
  const float* W2  = (const float*)d_in[4];
  const float* b2  = (const float*)d_in[5];
  const float* Wg1 = (const float*)d_in[6];
  const float* as1 = (const float*)d_in[7];
  const float* ad1 = (const float*)d_in[8];
  const float* bg1 = (const float*)d_in[9];
  const float* Wg2 = (const float*)d_in[10];
  const float* as2 = (const float*)d_in[11];
  const float* ad2 = (const float*)d_in[12];
  const float* bg2 = (const float*)d_in[13];
  float* out = (float*)d_out;

  char* w = (char*)d_ws;
  auto alloc = [&](size_t bytes) { char* p = w; w += (bytes + 255) & ~(size_t)255; return p; };
  u16* Hb     = (u16*)alloc((size_t)NN * 128 * 2);
  float* Hf   = (float*)alloc((size_t)NN * 128 * 4);
  float* dinv = (float*)alloc((size_t)NN * 4);
  float* asb  = (float*)alloc((size_t)NN * 2 * 4);
  float* adb  = (float*)alloc((size_t)NN * 2 * 4);
  int* rowp   = (int*)alloc((size_t)(NN + 1) * 4);
  int* csr    = (int*)alloc((size_t)EE * 4);
  u32* buf    = (u32*)alloc((size_t)NBC * CAPB * 4);
  int* gcnt   = (int*)alloc((size_t)NBC * 4);
  int* csrbase= (int*)alloc((size_t)NBC * 4);
  int* flag   = (int*)alloc(16);

  const int TB = 256;
  int gW = (NN + 3) / 4;          // wave per node
  int gG = (NN + 63) / 64;        // gemm blocks

  // CSR build: two-pass radix partition (LDS atomics only)
  k_probe<<<1, 256, 0, stream>>>(ei, flag, gcnt);
  k_part<<<256, TB, 0, stream>>>(ei, flag, gcnt, buf);
  k_scanb<<<1, 128, 0, stream>>>(gcnt, csrbase, rowp);
  k_csr2<<<NBC, TB, 0, stream>>>(buf, gcnt, csrbase, rowp, dinv, csr);

  // GCN 1
  k_gemm<128, 64, 64><<<gG, TB, 0, stream>>>(x, W1, Hb, NN);
  k_gcn<<<gW, TB, 0, stream>>>(Hb, dinv, rowp, csr, b1, Hf);
  // GCN 2
  k_gemm<64, 64, 64><<<gG, TB, 0, stream>>>(Hf, W2, Hb, NN);
  k_gcn<<<gW, TB, 0, stream>>>(Hb, dinv, rowp, csr, b2, Hf);
  // GAT 1 (concat, relu): gemm + fused att coefficients
  k_gemm_att<64, 128, 64, 32><<<gG, TB, 0, stream>>>(Hf, Wg1, as1, ad1, Hb, asb, adb, NN);
  k_gat1<<<gW, TB, 0, stream>>>(Hb, asb, adb, rowp, csr, bg1, Hf);
  // GAT 2 (head mean) + log_softmax
  k_gemm_att<128, 64, 64, 16><<<gG, TB, 0, stream>>>(Hf, Wg2, as2, ad2, Hb, asb, adb, NN);
  k_gat2<<<gW, TB, 0, stream>>>(Hb, asb, adb, rowp, csr, bg2, out);
}

// Round 8
// 224.129 us; speedup vs baseline: 2.1657x; 1.3656x over previous
//
#include <hip/hip_runtime.h>

#define NN 50000
#define EE 800000
#define NEG 0.2f
#define CAP 128    // per-wave LDS edge stash (deg ~Poisson(16), max ~45; fallback kept)
#define NBC 98     // coarse buckets of 512 nodes for CSR build
#define BSH2 9
#define CAPB 16384 // buf capacity per bucket (mean 8163 -> huge margin)
#define PCH 3125   // edges per k_part block (256 * 3125 == EE exactly)

typedef long long i64;
typedef unsigned int u32;
typedef unsigned short u16;
typedef __attribute__((ext_vector_type(8))) short bf16x8;
typedef __attribute__((ext_vector_type(4))) float f32x4;

static __device__ __forceinline__ float wave_max64(float v) {
#pragma unroll
  for (int m = 32; m >= 1; m >>= 1) v = fmaxf(v, __shfl_xor(v, m, 64));
  return v;
}
static __device__ __forceinline__ float wave_sum64(float v) {
#pragma unroll
  for (int m = 32; m >= 1; m >>= 1) v += __shfl_xor(v, m, 64);
  return v;
}

// bf16 helpers
static __device__ __forceinline__ u16 f2bf(float f) {
  u32 u = __float_as_uint(f);
  u += 0x7FFFu + ((u >> 16) & 1u);
  return (u16)(u >> 16);
}
static __device__ __forceinline__ float bflo(u32 v) { return __uint_as_float(v << 16); }
static __device__ __forceinline__ float bfhi(u32 v) { return __uint_as_float(v & 0xffff0000u); }
static __device__ __forceinline__ u32 pack2bf(float a, float b) {
  return (u32)f2bf(a) | ((u32)f2bf(b) << 16);
}

// ---- dtype probe + zero bucket counters ----------------------------------
__global__ void k_probe(const void* ei, int* flag, int* gcnt) {
  __shared__ int sbad[4];
  int t = threadIdx.x;
  if (t < NBC) gcnt[t] = 0;
  const i64* p = (const i64*)ei;
  i64 v = p[t];
  int bad = (v < 0 || v >= NN) ? 1 : 0;
  unsigned long long b = __ballot(bad);
  if ((t & 63) == 0) sbad[t >> 6] = (b != 0ULL);
  __syncthreads();
  if (t == 0) *flag = !(sbad[0] | sbad[1] | sbad[2] | sbad[3]);
}

static __device__ __forceinline__ int edge_at(const void* ei, int is64, int idx) {
  return is64 ? (int)((const i64*)ei)[idx] : ((const int*)ei)[idx];
}

// ---- pass 1: per-block LDS counting sort into 98 coarse buckets ----------
__global__ void k_part(const void* ei, const int* flag, int* gcnt, u32* buf) {
  __shared__ u32 lbuf[PCH];
  __shared__ int hist[128], offb[128], curb[128], gbase[128], sc[128];
  int t = threadIdx.x;
  int is64 = *flag;
  if (t < 128) { hist[t] = 0; curb[t] = 0; }
  __syncthreads();
  int lo = blockIdx.x * PCH;

  for (int e = lo + t; e < lo + PCH; e += 256)
    atomicAdd(&hist[edge_at(ei, is64, EE + e) >> BSH2], 1);
  __syncthreads();

  if (t < 128) sc[t] = hist[t];
  __syncthreads();
  for (int o = 1; o < 128; o <<= 1) {
    int v = (t >= o && t < 128) ? sc[t - o] : 0;
    __syncthreads();
    if (t < 128) sc[t] += v;
    __syncthreads();
  }
  if (t < 128) offb[t] = sc[t] - hist[t];
  __syncthreads();

  for (int e = lo + t; e < lo + PCH; e += 256) {
    int s = edge_at(ei, is64, e);
    int d = edge_at(ei, is64, EE + e);
    int b = d >> BSH2;
    u32 v = (u32)s | ((u32)(d & 511) << 16) | ((u32)b << 25);
    int p = atomicAdd(&curb[b], 1);
    lbuf[offb[b] + p] = v;
  }
  __syncthreads();

  if (t < 128) {
    int c = hist[t];
    gbase[t] = c ? atomicAdd(&gcnt[t], c) : 0;
  }
  __syncthreads();

  for (int i = t; i < PCH; i += 256) {
    u32 v = lbuf[i];
    int b = v >> 25;
    int pos = gbase[b] + (i - offb[b]);
    if (pos < CAPB) buf[(size_t)b * CAPB + pos] = v;
  }
}

// ---- pass 2: exclusive scan of bucket counts -----------------------------
__global__ void k_scanb(const int* gcnt, int* csrbase, int* rowp) {
  __shared__ int sc[128];
  int t = threadIdx.x;
  int c = (t < NBC) ? min(gcnt[t], CAPB) : 0;
  sc[t] = c;
  __syncthreads();
  for (int o = 1; o < 128; o <<= 1) {
    int v = (t >= o) ? sc[t - o] : 0;
    __syncthreads();
    sc[t] += v;
    __syncthreads();
  }
  if (t < NBC) csrbase[t] = sc[t] - c;
  if (t == 127) rowp[NN] = sc[127];
}

// ---- pass 3: per-bucket local sort -> rowp, dinv, csr --------------------
__global__ void k_csr2(const u32* __restrict__ buf, const int* __restrict__ gcnt,
                       const int* __restrict__ csrbase, int* __restrict__ rowp,
                       float* __restrict__ dinv, int* __restrict__ csr) {
  __shared__ int hist[512], offs[512], cur[512], sc[256];
  int b = blockIdx.x;
  int t = threadIdx.x;
  int cnt = min(gcnt[b], CAPB);
  const u32* mb = buf + (size_t)b * CAPB;
  int cbase = csrbase[b];
  int nbase = b << BSH2;
  int nn = min(512, NN - nbase);
  hist[t] = 0; hist[t + 256] = 0; cur[t] = 0; cur[t + 256] = 0;
  __syncthreads();
  for (int i = t; i < cnt; i += 256) atomicAdd(&hist[(mb[i] >> 16) & 511], 1);
  __syncthreads();
  int a0 = hist[2 * t], a1 = hist[2 * t + 1];
  sc[t] = a0 + a1;
  __syncthreads();
  for (int o = 1; o < 256; o <<= 1) {
    int v = (t >= o) ? sc[t - o] : 0;
    __syncthreads();
    sc[t] += v;
    __syncthreads();
  }
  int excl = sc[t] - (a0 + a1);
  offs[2 * t] = excl; offs[2 * t + 1] = excl + a0;
  __syncthreads();
  for (int i = t; i < nn; i += 256) {
    rowp[nbase + i] = cbase + offs[i];
    dinv[nbase + i] = rsqrtf((float)(hist[i] + 1));
  }
  for (int i = t; i < cnt; i += 256) {
    u32 v = mb[i];
    int dl = (v >> 16) & 511;
    int p = atomicAdd(&cur[dl], 1);
    csr[cbase + offs[dl] + p] = (int)(v & 0xFFFF);
  }
}

// ---- MFMA GEMM: Y(bf16)[M][N] = X[M][K] @ W[K][N], optional att epilogue -
// BM=64 rows/block, 4 waves, wave w = rows 16w..16w+15 x all N-tiles.
// LDS: A [BM][K] bf16 + Wt [N][K] bf16, both XOR-swizzled (byte ^= (row&7)<<4).
template <int K, int N, bool SRCF32, bool ATT, int NTH>
__global__ void k_mm(const void* __restrict__ Xsrc, const float* __restrict__ W,
                     const float* __restrict__ aw_s, const float* __restrict__ aw_d,
                     u16* __restrict__ Y, float* __restrict__ a_sv,
                     float* __restrict__ a_dv) {
  constexpr int BM = 64;
  constexpr int NT = N / 16;
  constexpr int KS = K / 32;
  __shared__ u16 Ab[BM * K];
  __shared__ u16 Wt[N * K];
  int t = threadIdx.x;
  int blockRow = blockIdx.x * BM;

  // stage A tile (fp32->bf16 or raw bf16 copy), swizzled
  if (SRCF32) {
    const float4* Xq = (const float4*)Xsrc + (size_t)blockRow * (K / 4);
    for (int i = t; i < BM * K / 4; i += 256) {
      int r = (i * 4) / K;
      float4 v = (blockRow + r < NN) ? Xq[i] : make_float4(0.f, 0.f, 0.f, 0.f);
      ushort4 p = make_ushort4(f2bf(v.x), f2bf(v.y), f2bf(v.z), f2bf(v.w));
      int b = i * 8;
      *(ushort4*)((char*)Ab + (b ^ ((r & 7) << 4))) = p;
    }
  } else {
    const int4* Xq = (const int4*)Xsrc + (size_t)blockRow * (K / 8);
    for (int i = t; i < BM * K / 8; i += 256) {
      int r = (i * 8) / K;
      int4 v = (blockRow + r < NN) ? Xq[i] : make_int4(0, 0, 0, 0);
      int b = i * 16;
      *(int4*)((char*)Ab + (b ^ ((r & 7) << 4))) = v;
    }
  }
  // stage W transposed (Wt[n][k]), swizzled; coalesced global reads
  for (int i = t; i < K * N; i += 256) {
    int k = i / N, n = i % N;
    int b = (n * K + k) * 2;
    *(u16*)((char*)Wt + (b ^ ((n & 7) << 4))) = f2bf(W[i]);
  }
  __syncthreads();

  int w = t >> 6, l = t & 63;
  int lr = l & 15, lg = l >> 4;
  int sw = (lr & 7) << 4;          // swizzle for rows read by this lane
  f32x4 acc[NT];
#pragma unroll
  for (int nt = 0; nt < NT; ++nt) acc[nt] = (f32x4)0.f;

#pragma unroll
  for (int ks = 0; ks < KS; ++ks) {
    int ar = 16 * w + lr;
    int ab = (ar * K + ks * 32 + lg * 8) * 2;
    bf16x8 af = *(bf16x8*)((char*)Ab + (ab ^ sw));
#pragma unroll
    for (int nt = 0; nt < NT; ++nt) {
      int bb = ((nt * 16 + lr) * K + ks * 32 + lg * 8) * 2;
      bf16x8 bfr = *(bf16x8*)((char*)Wt + (bb ^ sw));
      acc[nt] = __builtin_amdgcn_mfma_f32_16x16x32_bf16(af, bfr, acc[nt], 0, 0, 0);
    }
  }

  // store Y: D[row=(lg*4+j)][col=lr] per tile (m89-verified C/D layout)
#pragma unroll
  for (int j = 0; j < 4; ++j) {
    int row = blockRow + 16 * w + lg * 4 + j;
    if (row < NN) {
      u16* yr = Y + (size_t)row * N + lr;
#pragma unroll
      for (int nt = 0; nt < NT; ++nt) yr[nt * 16] = f2bf(acc[nt][j]);
    }
  }

  if (ATT) {
    float aws[NT], awd[NT];
#pragma unroll
    for (int nt = 0; nt < NT; ++nt) {
      aws[nt] = aw_s[nt * 16 + lr];
      awd[nt] = aw_d[nt * 16 + lr];
    }
#pragma unroll
    for (int j = 0; j < 4; ++j) {
      int row = blockRow + 16 * w + lg * 4 + j;
#pragma unroll
      for (int h = 0; h < 2; ++h) {
        float s = 0.f, d = 0.f;
#pragma unroll
        for (int q = 0; q < NTH; ++q) {
          int nt = h * NTH + q;
          s += acc[nt][j] * aws[nt];
          d += acc[nt][j] * awd[nt];
        }
#pragma unroll
        for (int mm = 8; mm >= 1; mm >>= 1) {
          s += __shfl_xor(s, mm, 64);
          d += __shfl_xor(d, mm, 64);
        }
        if (lr == 0 && row < NN) {
          a_sv[row * 2 + h] = s;
          a_dv[row * 2 + h] = d;
        }
      }
    }
  }
}

// ---- GCN aggregation: wave/node; halves alternate edges; bf16 out --------
__global__ void k_gcn(const u16* __restrict__ g, const float* __restrict__ dinv,
                      const int* __restrict__ rowp, const int* __restrict__ csr,
                      const float* __restrict__ bias, u16* __restrict__ outb) {
  __shared__ int   s_src[4][CAP];
  __shared__ float s_wt[4][CAP];
  int wid = (blockIdx.x * blockDim.x + threadIdx.x) >> 6;
  int w = (threadIdx.x >> 6) & 3;
  int lane = threadIdx.x & 63;
  if (wid >= NN) return;
  float di = dinv[wid];
  int beg = rowp[wid], cnt = rowp[wid + 1] - beg;
  int c1 = min(cnt, CAP);

  for (int idx = lane; idx < c1; idx += 64) {
    int s = csr[beg + idx];
    s_src[w][idx] = s; s_wt[w][idx] = dinv[s];
  }

  int half = lane >> 5, fp = lane & 31;
  const u32* g2 = (const u32*)g;
  float acc0 = 0.f, acc1 = 0.f;
  int idx = half;
  for (; idx + 6 < c1; idx += 8) {
    int sA = s_src[w][idx],     sB = s_src[w][idx + 2];
    int sC = s_src[w][idx + 4], sD = s_src[w][idx + 6];
    float wA = s_wt[w][idx],     wB = s_wt[w][idx + 2];
    float wC = s_wt[w][idx + 4], wD = s_wt[w][idx + 6];
    u32 vA = g2[(size_t)sA * 32 + fp], vB = g2[(size_t)sB * 32 + fp];
    u32 vC = g2[(size_t)sC * 32 + fp], vD = g2[(size_t)sD * 32 + fp];
    acc0 += bflo(vA) * wA + bflo(vB) * wB + bflo(vC) * wC + bflo(vD) * wD;
    acc1 += bfhi(vA) * wA + bfhi(vB) * wB + bfhi(vC) * wC + bfhi(vD) * wD;
  }
  for (; idx < c1; idx += 2) {
    int s = s_src[w][idx]; float ws = s_wt[w][idx];
    u32 v = g2[(size_t)s * 32 + fp];
    acc0 += bflo(v) * ws; acc1 += bfhi(v) * ws;
  }
  for (idx = CAP + half; idx < cnt; idx += 2) {
    int s = csr[beg + idx];
    float ws = dinv[s];
    u32 v = g2[(size_t)s * 32 + fp];
    acc0 += bflo(v) * ws; acc1 += bfhi(v) * ws;
  }
  if (half == 0) {
    u32 v = g2[(size_t)wid * 32 + fp];
    acc0 += bflo(v) * di; acc1 += bfhi(v) * di;
  }
  acc0 += __shfl_xor(acc0, 32, 64);
  acc1 += __shfl_xor(acc1, 32, 64);
  if (half == 0) {
    float v0 = fmaxf(acc0 * di + bias[2 * fp], 0.f);
    float v1 = fmaxf(acc1 * di + bias[2 * fp + 1], 0.f);
    ((u32*)outb)[(size_t)wid * 32 + fp] = pack2bf(v0, v1);
  }
}

// ---- GAT layer 1: wave per node, both heads; lane = dword 0..63 ----------
__global__ void k_gat1(const u16* __restrict__ hg, const float* __restrict__ a_s,
                       const float* __restrict__ a_d, const int* __restrict__ rowp,
                       const int* __restrict__ csr, const float* __restrict__ bias,
                       u16* __restrict__ outb) {
  __shared__ int   s_src[4][CAP];
  __shared__ float s_x0[4][CAP];
  __shared__ float s_x1[4][CAP];
  int wid = (blockIdx.x * blockDim.x + threadIdx.x) >> 6;
  int w = (threadIdx.x >> 6) & 3;
  int lane = threadIdx.x & 63;
  if (wid >= NN) return;
  int beg = rowp[wid], cnt = rowp[wid + 1] - beg;
  int tot = cnt + 1;
  int c1 = min(tot, CAP);
  float ad0 = a_d[wid * 2], ad1 = a_d[wid * 2 + 1];
  float m0, m1, inv0, inv1;

  if (tot <= 64) {
    bool act = lane < tot;
    int s = (lane < cnt) ? csr[beg + lane] : wid;
    float e0 = -1e30f, e1 = -1e30f;
    if (act) {
      float2 av = ((const float2*)a_s)[s];
      e0 = av.x + ad0; e0 = e0 > 0.f ? e0 : NEG * e0;
      e1 = av.y + ad1; e1 = e1 > 0.f ? e1 : NEG * e1;
    }
    m0 = wave_max64(e0); m1 = wave_max64(e1);
    float x0 = act ? __expf(e0 - m0) : 0.f;
    float x1 = act ? __expf(e1 - m1) : 0.f;
    inv0 = 1.f / wave_sum64(x0); inv1 = 1.f / wave_sum64(x1);
    if (act) { s_src[w][lane] = s; s_x0[w][lane] = x0; s_x1[w][lane] = x1; }
  } else {
    float mm0 = -1e30f, mm1 = -1e30f;
    for (int idx = lane; idx < tot; idx += 64) {
      int s = (idx < cnt) ? csr[beg + idx] : wid;
      float2 av = ((const float2*)a_s)[s];
      float e0 = av.x + ad0; e0 = e0 > 0.f ? e0 : NEG * e0;
      float e1 = av.y + ad1; e1 = e1 > 0.f ? e1 : NEG * e1;
      if (idx < CAP) { s_src[w][idx] = s; s_x0[w][idx] = e0; s_x1[w][idx] = e1; }
      mm0 = fmaxf(mm0, e0); mm1 = fmaxf(mm1, e1);
    }
    m0 = wave_max64(mm0); m1 = wave_max64(mm1);
    float ss0 = 0.f, ss1 = 0.f;
    for (int idx = lane; idx < c1; idx += 64) {
      float x0 = __expf(s_x0[w][idx] - m0), x1 = __expf(s_x1[w][idx] - m1);
      s_x0[w][idx] = x0; s_x1[w][idx] = x1;
      ss0 += x0; ss1 += x1;
    }
    for (int idx = CAP + lane; idx < tot; idx += 64) {
      int s = (idx < cnt) ? csr[beg + idx] : wid;
      float2 av = ((const float2*)a_s)[s];
      float e0 = av.x + ad0; e0 = e0 > 0.f ? e0 : NEG * e0;
      float e1 = av.y + ad1; e1 = e1 > 0.f ? e1 : NEG * e1;
      ss0 += __expf(e0 - m0); ss1 += __expf(e1 - m1);
    }
    inv0 = 1.f / wave_sum64(ss0); inv1 = 1.f / wave_sum64(ss1);
  }

  bool hi = (lane >= 32);
  float invh = hi ? inv1 : inv0, mh = hi ? m1 : m0, adh = hi ? ad1 : ad0;
  const u32* hg2 = (const u32*)hg;
  float acc0 = 0.f, acc1 = 0.f;
  int idx = 0;
  for (; idx + 3 < c1; idx += 4) {
    int sA = s_src[w][idx],     sB = s_src[w][idx + 1];
    int sC = s_src[w][idx + 2], sD = s_src[w][idx + 3];
    float aA = hi ? s_x1[w][idx]     : s_x0[w][idx];
    float aB = hi ? s_x1[w][idx + 1] : s_x0[w][idx + 1];
    float aC = hi ? s_x1[w][idx + 2] : s_x0[w][idx + 2];
    float aD = hi ? s_x1[w][idx + 3] : s_x0[w][idx + 3];
    u32 vA = hg2[(size_t)sA * 64 + lane], vB = hg2[(size_t)sB * 64 + lane];
    u32 vC = hg2[(size_t)sC * 64 + lane], vD = hg2[(size_t)sD * 64 + lane];
    acc0 += bflo(vA) * aA + bflo(vB) * aB + bflo(vC) * aC + bflo(vD) * aD;
    acc1 += bfhi(vA) * aA + bfhi(vB) * aB + bfhi(vC) * aC + bfhi(vD) * aD;
  }
  for (; idx < c1; ++idx) {
    int s = s_src[w][idx];
    float a = hi ? s_x1[w][idx] : s_x0[w][idx];
    u32 v = hg2[(size_t)s * 64 + lane];
    acc0 += bflo(v) * a; acc1 += bfhi(v) * a;
  }
  for (; idx < tot; ++idx) {
    int s = (idx < cnt) ? csr[beg + idx] : wid;
    float e = (hi ? a_s[s * 2 + 1] : a_s[s * 2]) + adh;
    e = e > 0.f ? e : NEG * e;
    float a = __expf(e - mh);
    u32 v = hg2[(size_t)s * 64 + lane];
    acc0 += bflo(v) * a; acc1 += bfhi(v) * a;
  }
  float v0 = fmaxf(acc0 * invh + bias[2 * lane], 0.f);
  float v1 = fmaxf(acc1 * invh + bias[2 * lane + 1], 0.f);
  ((u32*)outb)[(size_t)wid * 64 + lane] = pack2bf(v0, v1);
}

// ---- GAT layer 2 (H=2,C=32, head-mean) + log_softmax ---------------------
__global__ void k_gat2(const u16* __restrict__ hg, const float* __restrict__ a_s,
                       const float* __restrict__ a_d, const int* __restrict__ rowp,
                       const int* __restrict__ csr, const float* __restrict__ bias,
                       float* __restrict__ out) {
  __shared__ int   s_src[4][CAP];
  __shared__ float s_x0[4][CAP];
  __shared__ float s_x1[4][CAP];
  int wid = (blockIdx.x * blockDim.x + threadIdx.x) >> 6;
  int w = (threadIdx.x >> 6) & 3;
  int lane = threadIdx.x & 63;
  if (wid >= NN) return;
  int beg = rowp[wid], cnt = rowp[wid + 1] - beg;
  int tot = cnt + 1;
  int c1 = min(tot, CAP);
  float ad0 = a_d[wid * 2], ad1 = a_d[wid * 2 + 1];
  float m0, m1, inv0, inv1;

  if (tot <= 64) {
    bool act = lane < tot;
    int s = (lane < cnt) ? csr[beg + lane] : wid;
    float e0 = -1e30f, e1 = -1e30f;
    if (act) {
      float2 av = ((const float2*)a_s)[s];
      e0 = av.x + ad0; e0 = e0 > 0.f ? e0 : NEG * e0;
      e1 = av.y + ad1; e1 = e1 > 0.f ? e1 : NEG * e1;
    }
    m0 = wave_max64(e0); m1 = wave_max64(e1);
    float x0 = act ? __expf(e0 - m0) : 0.f;
    float x1 = act ? __expf(e1 - m1) : 0.f;
    inv0 = 1.f / wave_sum64(x0); inv1 = 1.f / wave_sum64(x1);
    if (act) { s_src[w][lane] = s; s_x0[w][lane] = x0; s_x1[w][lane] = x1; }
  } else {
    float mm0 = -1e30f, mm1 = -1e30f;
    for (int idx = lane; idx < tot; idx += 64) {
      int s = (idx < cnt) ? csr[beg + idx] : wid;
      float2 av = ((const float2*)a_s)[s];
      float e0 = av.x + ad0; e0 = e0 > 0.f ? e0 : NEG * e0;
      float e1 = av.y + ad1; e1 = e1 > 0.f ? e1 : NEG * e1;
      if (idx < CAP) { s_src[w][idx] = s; s_x0[w][idx] = e0; s_x1[w][idx] = e1; }
      mm0 = fmaxf(mm0, e0); mm1 = fmaxf(mm1, e1);
    }
    m0 = wave_max64(mm0); m1 = wave_max64(mm1);
    float ss0 = 0.f, ss1 = 0.f;
    for (int idx = lane; idx < c1; idx += 64) {
      float x0 = __expf(s_x0[w][idx] - m0), x1 = __expf(s_x1[w][idx] - m1);
      s_x0[w][idx] = x0; s_x1[w][idx] = x1;
      ss0 += x0; ss1 += x1;
    }
    for (int idx = CAP + lane; idx < tot; idx += 64) {
      int s = (idx < cnt) ? csr[beg + idx] : wid;
      float2 av = ((const float2*)a_s)[s];
      float e0 = av.x + ad0; e0 = e0 > 0.f ? e0 : NEG * e0;
      float e1 = av.y + ad1; e1 = e1 > 0.f ? e1 : NEG * e1;
      ss0 += __expf(e0 - m0); ss1 += __expf(e1 - m1);
    }
    inv0 = 1.f / wave_sum64(ss0); inv1 = 1.f / wave_sum64(ss1);
  }

  int half = lane >> 5, fp = lane & 31;
  int hh2 = fp >> 4;
  float invh = hh2 ? inv1 : inv0;
  float mh = hh2 ? m1 : m0;
  float adh = hh2 ? ad1 : ad0;

  const u32* hg2 = (const u32*)hg;
  float acc0 = 0.f, acc1 = 0.f;
  int idx = half;
  for (; idx + 6 < c1; idx += 8) {
    int sA = s_src[w][idx],     sB = s_src[w][idx + 2];
    int sC = s_src[w][idx + 4], sD = s_src[w][idx + 6];
    float aA = hh2 ? s_x1[w][idx]     : s_x0[w][idx];
    float aB = hh2 ? s_x1[w][idx + 2] : s_x0[w][idx + 2];
    float aC = hh2 ? s_x1[w][idx + 4] : s_x0[w][idx + 4];
    float aD = hh2 ? s_x1[w][idx + 6] : s_x0[w][idx + 6];
    u32 vA = hg2[(size_t)sA * 32 + fp], vB = hg2[(size_t)sB * 32 + fp];
    u32 vC = hg2[(size_t)sC * 32 + fp], vD = hg2[(size_t)sD * 32 + fp];
    acc0 += bflo(vA) * aA + bflo(vB) * aB + bflo(vC) * aC + bflo(vD) * aD;
    acc1 += bfhi(vA) * aA + bfhi(vB) * aB + bfhi(vC) * aC + bfhi(vD) * aD;
  }
  for (; idx < c1; idx += 2) {
    int s = s_src[w][idx];
    float a = hh2 ? s_x1[w][idx] : s_x0[w][idx];
    u32 v = hg2[(size_t)s * 32 + fp];
    acc0 += bflo(v) * a; acc1 += bfhi(v) * a;
  }
  for (idx = CAP + half; idx < tot; idx += 2) {
    int s = (idx < cnt) ? csr[beg + idx] : wid;
    float e = a_s[s * 2 + hh2] + adh;
    e = e > 0.f ? e : NEG * e;
    float a = __expf(e - mh);
    u32 v = hg2[(size_t)s * 32 + fp];
    acc0 += bflo(v) * a; acc1 += bfhi(v) * a;
  }
  acc0 += __shfl_xor(acc0, 32, 64);
  acc1 += __shfl_xor(acc1, 32, 64);

  float v0 = acc0 * invh, v1 = acc1 * invh;
  v0 = 0.5f * (v0 + __shfl_xor(v0, 16, 64));
  v1 = 0.5f * (v1 + __shfl_xor(v1, 16, 64));
  int c0 = 2 * (fp & 15);
  v0 += bias[c0]; v1 += bias[c0 + 1];
  float mx = fmaxf(v0, v1);
#pragma unroll
  for (int m = 8; m >= 1; m >>= 1) mx = fmaxf(mx, __shfl_xor(mx, m, 64));
  float se = __expf(v0 - mx) + __expf(v1 - mx);
#pragma unroll
  for (int m = 8; m >= 1; m >>= 1) se += __shfl_xor(se, m, 64);
  float lse = mx + __logf(se);
  if (lane < 16) ((float2*)(out + (size_t)wid * 32))[fp] = make_float2(v0 - lse, v1 - lse);
}

// --------------------------------------------------------------------------
extern "C" void kernel_launch(void* const* d_in, const int* in_sizes, int n_in,
                              void* d_out, int out_size, void* d_ws, size_t ws_size,
                              hipStream_t stream) {
  (void)in_sizes; (void)n_in; (void)out_size; (void)ws_size;
  const float* x   = (const float*)d_in[0];
  const void*  ei  = d_in[1];
  const float* W1  = (const float*)d_in[2];
  const float* b1  = (const float*)d_in[3];
  const float* W2  = (const float*)d_in[4];
  const float* b2  = (const float*)d_in[5];
  const float* Wg1 = (const float*)d_in[6];
  const float* as1 = (const float*)d_in[7];
  const float* ad1 = (const float*)d_in[8];
  const float* bg1 = (const float*)d_in[9];
  const float* Wg2 = (const float*)d_in[10];
  const float* as2 = (const float*)d_in[11];
  const float* ad2 = (const float*)d_in[12];
  const float* bg2 = (const float*)d_in[13];
  float* out = (float*)d_out;

  char* w = (char*)d_ws;
  auto alloc = [&](size_t bytes) { char* p = w; w += (bytes + 255) & ~(size_t)255; return p; };
  u16* Hb     = (u16*)alloc((size_t)NN * 128 * 2);   // GEMM outputs (bf16)
  u16* Xb     = (u16*)alloc((size_t)NN * 128 * 2);   // aggregation outputs (bf16)
  float* dinv = (float*)alloc((size_t)NN * 4);
  float* asb  = (float*)alloc((size_t)NN * 2 * 4);
  float* adb  = (float*)alloc((size_t)NN * 2 * 4);
  int* rowp   = (int*)alloc((size_t)(NN + 1) * 4);
  int* csr    = (int*)alloc((size_t)EE * 4);
  u32* buf    = (u32*)alloc((size_t)NBC * CAPB * 4);
  int* gcnt   = (int*)alloc((size_t)NBC * 4);
  int* csrbase= (int*)alloc((size_t)NBC * 4);
  int* flag   = (int*)alloc(16);

  const int TB = 256;
  int gW = (NN + 3) / 4;            // wave per node
  int gG = (NN + 63) / 64;          // 64-row GEMM blocks

  // CSR build (two-pass radix partition)
  k_probe<<<1, 256, 0, stream>>>(ei, flag, gcnt);
  k_part<<<256, TB, 0, stream>>>(ei, flag, gcnt, buf);
  k_scanb<<<1, 128, 0, stream>>>(gcnt, csrbase, rowp);
  k_csr2<<<NBC, TB, 0, stream>>>(buf, gcnt, csrbase, rowp, dinv, csr);

  // GCN 1
  k_mm<128, 64, true, false, 0><<<gG, TB, 0, stream>>>(x, W1, nullptr, nullptr, Hb, nullptr, nullptr);
  k_gcn<<<gW, TB, 0, stream>>>(Hb, dinv, rowp, csr, b1, Xb);
  // GCN 2
  k_mm<64, 64, false, false, 0><<<gG, TB, 0, stream>>>(Xb, W2, nullptr, nullptr, Hb, nullptr, nullptr);
  k_gcn<<<gW, TB, 0, stream>>>(Hb, dinv, rowp, csr, b2, Xb);
  // GAT 1 (concat, relu) + fused att coefficients
  k_mm<64, 128, false, true, 4><<<gG, TB, 0, stream>>>(Xb, Wg1, as1, ad1, Hb, asb, adb);
  k_gat1<<<gW, TB, 0, stream>>>(Hb, asb, adb, rowp, csr, bg1, Xb);
  // GAT 2 (head mean) + log_softmax, fused att coefficients
  k_mm<128, 64, false, true, 2><<<gG, TB, 0, stream>>>(Xb, Wg2, as2, ad2, Hb, asb, adb);
  k_gat2<<<gW, TB, 0, stream>>>(Hb, asb, adb, rowp, csr, bg2, out);
}